// Round 6
// baseline (704.111 us; speedup 1.0000x reference)
//
#include <hip/hip_runtime.h>

// CortexNetwork: aff + 0.9*exc - 0.9*inh, relu, broadcast over C.
// History: R2 all-temporal 2.6 TB/s (MSHR cap) -> R3 nt loads ~4.3 TB/s.
// R4 (deep batch) & R5 (wave-uniform rows) neutral -> read-path ceiling.
// R6: (a) route affW through the temporal path (laterals stay nt) to test
// path overlap; (b) fuse phase2 into phase1 via device-scope counter per ij
// (last split-block writes the 16 outputs) - removes a dispatch + drain.

constexpr int C   = 16;
constexpr int GX  = 36;
constexpr int GY  = 36;
constexpr int RF  = 24;
constexpr int IMG = 64;
constexpr int GG  = GX * GY;   // 1296
constexpr int RR  = RF * RF;   // 576
constexpr int SPLIT = 4;
constexpr int CPB   = C / SPLIT;   // 4 channels per block

typedef float f4 __attribute__((ext_vector_type(4)));

__global__ __launch_bounds__(256)
void cortex_fused(const float* __restrict__ x,
                  const float* __restrict__ prev,
                  const float* __restrict__ affW,
                  const float* __restrict__ exW,
                  const float* __restrict__ inW,
                  const int*   __restrict__ rx,
                  const int*   __restrict__ ry,
                  float* __restrict__ partial,
                  int*   __restrict__ cnt,
                  float* __restrict__ out)
{
    const int bid   = blockIdx.x;
    const int ij    = bid % GG;          // adjacent bids -> adjacent ij, same split
    const int split = bid / GG;
    const int cs    = split * CPB;
    const int i = ij / GY;
    const int j = ij - i * GY;
    const int t = threadIdx.x;

    const int rxi = rx[i];
    const int ryj = ry[j];

    float acc = 0.0f;

    // ---- Afferent: 4 ch x 144 float4 of affW, TEMPORAL path (L1);
    //      x gathered via L1/L2 (reused across blocks) ----
    if (t < RR / 4) {
        const int u  = t / (RF / 4);
        const int v0 = 4 * (t - u * (RF / 4));
        f4 w[CPB];
        #pragma unroll
        for (int cc = 0; cc < CPB; ++cc) {
            const int c = cs + cc;
            w[cc] = ((const f4*)(affW + ((size_t)c * GG + ij) * RR))[t];
        }
        #pragma unroll
        for (int cc = 0; cc < CPB; ++cc) {
            const int c = cs + cc;
            const float* xp = x + ((c * IMG + rxi + u) * IMG + ryj + v0);
            acc = fmaf(w[cc].x, xp[0], acc);
            acc = fmaf(w[cc].y, xp[1], acc);
            acc = fmaf(w[cc].z, xp[2], acc);
            acc = fmaf(w[cc].w, xp[3], acc);
        }
    }

    // ---- Lateral: 4 ch x 324 f4 from each of exW, inW — NT path ----
    float d[CPB] = {0.0f, 0.0f, 0.0f, 0.0f};
    for (int k = t; k < GG / 4; k += 256) {
        f4 e[CPB], h[CPB];
        #pragma unroll
        for (int cc = 0; cc < CPB; ++cc) {
            const size_t base = ((size_t)(cs + cc) * GG + ij) * GG;
            e[cc] = __builtin_nontemporal_load((const f4*)(exW + base) + k);
            h[cc] = __builtin_nontemporal_load((const f4*)(inW + base) + k);
        }
        #pragma unroll
        for (int cc = 0; cc < CPB; ++cc)
            d[cc] += (e[cc].x + e[cc].y + e[cc].z + e[cc].w)
                   - (h[cc].x + h[cc].y + h[cc].z + h[cc].w);
    }
    {
        float lat = 0.0f;
        #pragma unroll
        for (int cc = 0; cc < CPB; ++cc)
            lat = fmaf(prev[(cs + cc) * GG + ij], d[cc], lat);
        acc = fmaf(0.9f, lat, acc);
    }

    // ---- Block reduction ----
    for (int off = 32; off > 0; off >>= 1)
        acc += __shfl_down(acc, off, 64);

    __shared__ float sred[4];
    const int wave = t >> 6;
    const int lane = t & 63;
    if (lane == 0) sred[wave] = acc;
    __syncthreads();

    // ---- Tail fusion: last split-block for this ij writes the output ----
    if (t == 0) {
        const float psum = sred[0] + sred[1] + sred[2] + sred[3];
        __hip_atomic_store(&partial[split * GG + ij], psum,
                           __ATOMIC_RELEASE, __HIP_MEMORY_SCOPE_AGENT);
        const int prevCnt = __hip_atomic_fetch_add(&cnt[ij], 1,
                           __ATOMIC_ACQ_REL, __HIP_MEMORY_SCOPE_AGENT);
        if (prevCnt == SPLIT - 1) {
            float tot = 0.0f;
            #pragma unroll
            for (int s = 0; s < SPLIT; ++s)
                tot += __hip_atomic_load(&partial[s * GG + ij],
                           __ATOMIC_RELAXED, __HIP_MEMORY_SCOPE_AGENT);
            const float a = fmaxf(tot, 0.0f);
            #pragma unroll
            for (int c = 0; c < C; ++c)
                out[c * GG + ij] = a;
        }
    }
}

extern "C" void kernel_launch(void* const* d_in, const int* in_sizes, int n_in,
                              void* d_out, int out_size, void* d_ws, size_t ws_size,
                              hipStream_t stream) {
    const float* x     = (const float*)d_in[0];
    const float* prev  = (const float*)d_in[1];
    const float* affW  = (const float*)d_in[2];
    const float* exW   = (const float*)d_in[3];
    const float* inW   = (const float*)d_in[4];
    const int*   rx    = (const int*)d_in[5];
    const int*   ry    = (const int*)d_in[6];
    float* out = (float*)d_out;

    float* partial = (float*)d_ws;                  // SPLIT*GG floats
    int*   cnt     = (int*)((char*)d_ws + SPLIT * GG * sizeof(float));

    hipMemsetAsync(cnt, 0, GG * sizeof(int), stream);
    cortex_fused<<<GG * SPLIT, 256, 0, stream>>>(x, prev, affW, exW, inW,
                                                 rx, ry, partial, cnt, out);
}